// Round 7
// baseline (641.961 us; speedup 1.0000x reference)
//
#include <hip/hip_runtime.h>
#include <hip/hip_bf16.h>

#define NN   100000
#define EE   3200000
#define KDIM 1433
#define HID  16
#define H2P  8
#define OUTD 7

// ---- gemm1 tiling ----
#define KC    64
#define RB    64
#define XSTR  69             // 69 mod 32 = 5, coprime -> 2-way LDS aliasing = free
#define NCHUNK ((KDIM + KC - 1) / KC)   // 23
#define NTIL  ((NN + RB - 1) / RB)      // 1563  (<= 2048 slots at 8 blocks/CU -> single round)

// ---- scan tiling ----
#define SCAN_TPB   1024
#define SCAN_ELEMS 4096
#define NB_SCAN    ((NN + SCAN_ELEMS - 1) / SCAN_ELEMS)   // 25

__device__ inline unsigned short f2bf(float f) {        // fp32 -> bf16 rn
    unsigned u = __float_as_uint(f);
    unsigned r = (u + 0x7FFFu + ((u >> 16) & 1u)) >> 16;
    return (unsigned short)r;
}

// ============================ degree / norm / CSR ============================

__global__ void k_zero_i32(int* __restrict__ p, int n) {
    int i = blockIdx.x * blockDim.x + threadIdx.x;
    if (i < n) p[i] = 0;
}

// 4 edges per thread (EE % 4 == 0)
__global__ void k_count4(const int* __restrict__ ei, int* __restrict__ cnt) {
    int t = blockIdx.x * blockDim.x + threadIdx.x;
    if (t >= EE / 4) return;
    int4 r4 = reinterpret_cast<const int4*>(ei)[t];
    atomicAdd(&cnt[r4.x], 1);
    atomicAdd(&cnt[r4.y], 1);
    atomicAdd(&cnt[r4.z], 1);
    atomicAdd(&cnt[r4.w], 1);
}

__global__ void k_dinv_from_cnt(const int* __restrict__ cnt, float* __restrict__ dinv) {
    int i = blockIdx.x * blockDim.x + threadIdx.x;
    if (i < NN) dinv[i] = rsqrtf((float)cnt[i] + 1.0f);   // +1 self-loop
}

// per-block scan; also emits dinv (fused)
__global__ __launch_bounds__(SCAN_TPB) void k_scan1(const int* __restrict__ cnt,
                                                    int* __restrict__ rowptr,
                                                    int* __restrict__ bsum,
                                                    float* __restrict__ dinv) {
    __shared__ int spart[16];
    const int tid = threadIdx.x;
    const int L = tid & 63;
    const int w = tid >> 6;
    const int i0 = blockIdx.x * SCAN_ELEMS + tid * 4;
    int v0 = (i0 + 0 < NN) ? cnt[i0 + 0] : 0;
    int v1 = (i0 + 1 < NN) ? cnt[i0 + 1] : 0;
    int v2 = (i0 + 2 < NN) ? cnt[i0 + 2] : 0;
    int v3 = (i0 + 3 < NN) ? cnt[i0 + 3] : 0;
    if (i0 + 0 < NN) dinv[i0 + 0] = rsqrtf((float)v0 + 1.0f);
    if (i0 + 1 < NN) dinv[i0 + 1] = rsqrtf((float)v1 + 1.0f);
    if (i0 + 2 < NN) dinv[i0 + 2] = rsqrtf((float)v2 + 1.0f);
    if (i0 + 3 < NN) dinv[i0 + 3] = rsqrtf((float)v3 + 1.0f);
    int local = v0 + v1 + v2 + v3;
    int s = local;
#pragma unroll
    for (int ofs = 1; ofs < 64; ofs <<= 1) {
        int n = __shfl_up(s, ofs, 64);
        if (L >= ofs) s += n;
    }
    if (L == 63) spart[w] = s;
    __syncthreads();
    if (w == 0) {
        int p = (L < 16) ? spart[L] : 0;
#pragma unroll
        for (int ofs = 1; ofs < 16; ofs <<= 1) {
            int n = __shfl_up(p, ofs, 64);
            if (L >= ofs) p += n;
        }
        if (L < 16) spart[L] = p;
    }
    __syncthreads();
    int waveoff = (w > 0) ? spart[w - 1] : 0;
    int excl = waveoff + s - local;                 // block-local exclusive
    if (i0 + 0 < NN) { rowptr[i0 + 0] = excl; excl += v0; }
    if (i0 + 1 < NN) { rowptr[i0 + 1] = excl; excl += v1; }
    if (i0 + 2 < NN) { rowptr[i0 + 2] = excl; excl += v2; }
    if (i0 + 3 < NN) { rowptr[i0 + 3] = excl; excl += v3; }
    if (tid == 0) bsum[blockIdx.x] = spart[15];
}

__global__ void k_scan2(const int* __restrict__ bsum, int* __restrict__ boffs,
                        int* __restrict__ rowptr) {
    int L = threadIdx.x;   // one wave
    int v = (L < NB_SCAN) ? bsum[L] : 0;
    int s = v;
#pragma unroll
    for (int ofs = 1; ofs < 64; ofs <<= 1) {
        int n = __shfl_up(s, ofs, 64);
        if (L >= ofs) s += n;
    }
    if (L < NB_SCAN) boffs[L] = s - v;
    if (L == NB_SCAN - 1) rowptr[NN] = s;          // grand total (=EE)
}

__global__ __launch_bounds__(SCAN_TPB) void k_scan3(const int* __restrict__ boffs,
                                                    int* __restrict__ rowptr,
                                                    int* __restrict__ cursor) {
    const int off = boffs[blockIdx.x];
    const int i0 = blockIdx.x * SCAN_ELEMS + threadIdx.x * 4;
#pragma unroll
    for (int t = 0; t < 4; ++t) {
        int i = i0 + t;
        if (i < NN) {
            int v = rowptr[i] + off;
            rowptr[i] = v;
            cursor[i] = v;
        }
    }
}

// 4 edges per thread
__global__ void k_place4(const int* __restrict__ ei, int* __restrict__ cursor,
                         int* __restrict__ scol) {
    int t = blockIdx.x * blockDim.x + threadIdx.x;
    if (t >= EE / 4) return;
    int4 r4 = reinterpret_cast<const int4*>(ei)[t];
    int4 c4 = reinterpret_cast<const int4*>(ei + EE)[t];
    int p;
    p = atomicAdd(&cursor[r4.x], 1); scol[p] = c4.x;
    p = atomicAdd(&cursor[r4.y], 1); scol[p] = c4.y;
    p = atomicAdd(&cursor[r4.z], 1); scol[p] = c4.z;
    p = atomicAdd(&cursor[r4.w], 1); scol[p] = c4.w;
}

// ============================ layer 1 GEMM ============================

// h1[N][16] = x[N][1433] @ W1[1433][16], 64-row tiles, KC=64 chunks.
// LDS 17.3 KB + VGPR<=64 (launch_bounds 256,8) -> 8 blocks/CU = 2048 slots:
// all 1563 blocks resident simultaneously -> single scheduling round.
// tmp[16] register prefetch rotation hides HBM latency under the FMA phase.
__global__ __launch_bounds__(256, 8) void k_gemm1(const float* __restrict__ x,
                                                  const float* __restrict__ W1,
                                                  const float* __restrict__ dscale,
                                                  unsigned short* __restrict__ h1b,
                                                  float* __restrict__ h1f) {
    __shared__ __align__(16) float xs[RB * XSTR];   // 17664 B
    const int tid = threadIdx.x;
    const int wu  = __builtin_amdgcn_readfirstlane(tid >> 6);  // W1 loads -> s_load
    const int L   = tid & 63;
    const int r0  = blockIdx.x * RB;
    const int kk    = tid & 63;
    const int rbase = tid >> 6;              // 0..3
    const bool fullrows = (r0 + RB) <= NN;

    float tmp[16];
    float acc[HID];
#pragma unroll
    for (int j = 0; j < HID; ++j) acc[j] = 0.f;

    auto stage = [&](int c) {
        const int c0t = c * KC;
        const int kv  = KDIM - c0t;          // >= KC except last chunk
        const float* xp = x + (size_t)(r0 + rbase) * KDIM + c0t + kk;
        if (fullrows && kv >= KC) {
#pragma unroll
            for (int m = 0; m < 16; ++m) tmp[m] = xp[(size_t)(4 * m) * KDIM];
        } else {
            const bool kok = kk < kv;
#pragma unroll
            for (int m = 0; m < 16; ++m) {
                int gr = r0 + rbase + 4 * m;
                tmp[m] = (kok && gr < NN) ? xp[(size_t)(4 * m) * KDIM] : 0.f;
            }
        }
    };

    stage(0);                                // prologue

    for (int c = 0; c < NCHUNK; ++c) {
        const int c0 = c * KC;
        const int kvalid = (KDIM - c0 < KC) ? (KDIM - c0) : KC;
        __syncthreads();                     // xs free (prev compute done)
#pragma unroll
        for (int m = 0; m < 16; ++m) {       // vmcnt drain happens here
            xs[(rbase + 4 * m) * XSTR + kk] = tmp[m];
        }
        __syncthreads();

        if (c + 1 < NCHUNK) stage(c + 1);    // prefetch overlaps compute below

        // wave wu covers kk in [wu*16, wu*16+16); W1 address uniform -> s_load
        int kend = kvalid - wu * 16;
        kend = kend < 0 ? 0 : (kend > 16 ? 16 : kend);
        const float* wbase = W1 + (size_t)(c0 + wu * 16) * HID;
        const float* xbase = xs + L * XSTR + wu * 16;
#pragma unroll 4
        for (int i = 0; i < kend; ++i) {
            float xv = xbase[i];
            const float* wr = wbase + i * HID;
#pragma unroll
            for (int j = 0; j < HID; ++j) acc[j] = fmaf(xv, wr[j], acc[j]);
        }
    }

    // ---- epilogue: cross-wave k-reduction via LDS (16 KB <= 17.3 KB) ----
    __syncthreads();
    float4* red4 = reinterpret_cast<float4*>(xs);
    red4[(wu * 64 + L) * 4 + 0] = make_float4(acc[0], acc[1], acc[2], acc[3]);
    red4[(wu * 64 + L) * 4 + 1] = make_float4(acc[4], acc[5], acc[6], acc[7]);
    red4[(wu * 64 + L) * 4 + 2] = make_float4(acc[8], acc[9], acc[10], acc[11]);
    red4[(wu * 64 + L) * 4 + 3] = make_float4(acc[12], acc[13], acc[14], acc[15]);
    __syncthreads();
    int rr = tid >> 2, jj = tid & 3;
    float4 a = red4[(0 * 64 + rr) * 4 + jj];
    float4 b = red4[(1 * 64 + rr) * 4 + jj];
    float4 cf = red4[(2 * 64 + rr) * 4 + jj];
    float4 d = red4[(3 * 64 + rr) * 4 + jj];
    float4 s = make_float4(a.x + b.x + cf.x + d.x, a.y + b.y + cf.y + d.y,
                           a.z + b.z + cf.z + d.z, a.w + b.w + cf.w + d.w);
    int gr = r0 + rr;
    if (gr < NN) {
        if (h1b) {
            float sc = dscale[gr];
            unsigned u0 = (unsigned)f2bf(s.x * sc) | ((unsigned)f2bf(s.y * sc) << 16);
            unsigned u1 = (unsigned)f2bf(s.z * sc) | ((unsigned)f2bf(s.w * sc) << 16);
            reinterpret_cast<uint2*>(h1b)[(size_t)gr * 4 + jj] = make_uint2(u0, u1);
        } else {
            reinterpret_cast<float4*>(h1f)[(size_t)gr * 4 + jj] = s;
        }
    }
}

// ============================ fused CSR aggregation + layer-2 matvec ============================

__global__ __launch_bounds__(256) void k_agg1m(const int* __restrict__ rowptr,
                                               const int* __restrict__ scol,
                                               const float* __restrict__ dinv,
                                               const unsigned short* __restrict__ h1b,
                                               const float* __restrict__ b1,
                                               const float* __restrict__ W2,
                                               float* __restrict__ h2s) {
    int row = blockIdx.x * 4 + (threadIdx.x >> 6);
    int L = threadIdx.x & 63;
    int ee = L >> 2;        // 0..15 edge slot
    int q  = L & 3;         // quarter of the 16-feature row
    int s = rowptr[row], eend = rowptr[row + 1];
    float dr = dinv[row];
    const uint2* h1q = reinterpret_cast<const uint2*>(h1b);
    float4 acc = make_float4(0.f, 0.f, 0.f, 0.f);
    for (int k = s + ee; k < eend; k += 16) {
        int c = scol[k];
        uint2 hv = h1q[(size_t)c * 4 + q];
        acc.x += __uint_as_float(hv.x << 16);
        acc.y += __uint_as_float(hv.x & 0xFFFF0000u);
        acc.z += __uint_as_float(hv.y << 16);
        acc.w += __uint_as_float(hv.y & 0xFFFF0000u);
    }
#pragma unroll
    for (int mask = 4; mask <= 32; mask <<= 1) {
        acc.x += __shfl_xor(acc.x, mask, 64);
        acc.y += __shfl_xor(acc.y, mask, 64);
        acc.z += __shfl_xor(acc.z, mask, 64);
        acc.w += __shfl_xor(acc.w, mask, 64);
    }
    uint2 sv = h1q[(size_t)row * 4 + q];          // self term (already *dinv[row])
    acc.x = (acc.x + __uint_as_float(sv.x << 16)) * dr;
    acc.y = (acc.y + __uint_as_float(sv.x & 0xFFFF0000u)) * dr;
    acc.z = (acc.z + __uint_as_float(sv.y << 16)) * dr;
    acc.w = (acc.w + __uint_as_float(sv.y & 0xFFFF0000u)) * dr;
    float v[16];
#pragma unroll
    for (int qq = 0; qq < 4; ++qq) {
        int src = (L & ~3) | qq;
        v[qq * 4 + 0] = __shfl(acc.x, src, 64);
        v[qq * 4 + 1] = __shfl(acc.y, src, 64);
        v[qq * 4 + 2] = __shfl(acc.z, src, 64);
        v[qq * 4 + 3] = __shfl(acc.w, src, 64);
    }
#pragma unroll
    for (int k = 0; k < 16; ++k) v[k] = fmaxf(v[k] + b1[k], 0.f);
    if (L < 8) {
        int j = (L < 7) ? L : 0;
        float o = 0.f;
#pragma unroll
        for (int k = 0; k < 16; ++k) o = fmaf(v[k], W2[k * 7 + j], o);
        h2s[(size_t)row * H2P + L] = (L < 7) ? o * dr : 0.f;
    }
}

__global__ __launch_bounds__(256) void k_agg2(const int* __restrict__ rowptr,
                                              const int* __restrict__ scol,
                                              const float* __restrict__ dinv,
                                              const float* __restrict__ h2s,
                                              const float* __restrict__ b2,
                                              float* __restrict__ out) {
    int row = blockIdx.x * 4 + (threadIdx.x >> 6);
    int L = threadIdx.x & 63;
    int ee = L >> 3, j = L & 7;
    int s = rowptr[row], eend = rowptr[row + 1];
    float dr = dinv[row];
    float acc = 0.f;
    for (int k = s + ee; k < eend; k += 8) {
        int c = scol[k];
        acc += h2s[(size_t)c * H2P + j];
    }
    acc += __shfl_xor(acc, 8, 64);
    acc += __shfl_xor(acc, 16, 64);
    acc += __shfl_xor(acc, 32, 64);
    acc += h2s[(size_t)row * H2P + j];
    float v = acc * dr + ((j < 7) ? b2[j] : 0.f);
    if (j == 7) v = -3.0e38f;
    float m = v;
    m = fmaxf(m, __shfl_xor(m, 1, 64));
    m = fmaxf(m, __shfl_xor(m, 2, 64));
    m = fmaxf(m, __shfl_xor(m, 4, 64));
    float ex = (j < 7) ? expf(v - m) : 0.f;
    float ssum = ex;
    ssum += __shfl_xor(ssum, 1, 64);
    ssum += __shfl_xor(ssum, 2, 64);
    ssum += __shfl_xor(ssum, 4, 64);
    float ls = logf(ssum);
    if (j < 7) out[(size_t)row * OUTD + j] = v - m - ls;
}

// ============================ fallback (small ws): atomic path ============================

__global__ void k_selfloop1(const float* __restrict__ h1, const float* __restrict__ dinv,
                            float* __restrict__ agg1) {
    int t = blockIdx.x * blockDim.x + threadIdx.x;
    if (t >= NN * HID) return;
    int i = t >> 4;
    float di = dinv[i];
    agg1[t] = h1[t] * di * di;
}

__global__ void k_scatter1f(const int* __restrict__ ei, const float* __restrict__ dinv,
                            const float* __restrict__ h1, float* __restrict__ agg1) {
    int t = blockIdx.x * blockDim.x + threadIdx.x;
    int e = t >> 4, j = t & 15;
    if (e >= EE) return;
    int r = ei[e], c = ei[EE + e];
    float nrm = dinv[r] * dinv[c];
    atomicAdd(&agg1[(size_t)r * HID + j], h1[(size_t)c * HID + j] * nrm);
}

__global__ void k_mlp2(const float* __restrict__ agg1, const float* __restrict__ b1,
                       const float* __restrict__ W2, const float* __restrict__ dinv,
                       float* __restrict__ h2p, float* __restrict__ agg2p) {
    int i = blockIdx.x * blockDim.x + threadIdx.x;
    if (i >= NN) return;
    const float4* a4 = reinterpret_cast<const float4*>(agg1 + (size_t)i * HID);
    float4 t0 = a4[0], t1 = a4[1], t2 = a4[2], t3 = a4[3];
    float v[16] = {t0.x, t0.y, t0.z, t0.w, t1.x, t1.y, t1.z, t1.w,
                   t2.x, t2.y, t2.z, t2.w, t3.x, t3.y, t3.z, t3.w};
#pragma unroll
    for (int k = 0; k < 16; ++k) v[k] = fmaxf(v[k] + b1[k], 0.f);
    float o[8] = {0.f, 0.f, 0.f, 0.f, 0.f, 0.f, 0.f, 0.f};
#pragma unroll
    for (int k = 0; k < 16; ++k)
#pragma unroll
        for (int j = 0; j < 7; ++j) o[j] = fmaf(v[k], W2[k * 7 + j], o[j]);
    float4* hp = reinterpret_cast<float4*>(h2p + (size_t)i * H2P);
    hp[0] = make_float4(o[0], o[1], o[2], o[3]);
    hp[1] = make_float4(o[4], o[5], o[6], 0.f);
    if (agg2p) {
        float di = dinv[i];
        float d2 = di * di;
        float4* ap = reinterpret_cast<float4*>(agg2p + (size_t)i * H2P);
        ap[0] = make_float4(o[0] * d2, o[1] * d2, o[2] * d2, o[3] * d2);
        ap[1] = make_float4(o[4] * d2, o[5] * d2, o[6] * d2, 0.f);
    }
}

__global__ void k_scatter2f(const int* __restrict__ ei, const float* __restrict__ dinv,
                            const float* __restrict__ h2p, float* __restrict__ agg2p) {
    int t = blockIdx.x * blockDim.x + threadIdx.x;
    int e = t >> 3, j = t & 7;
    if (e >= EE || j >= OUTD) return;
    int r = ei[e], c = ei[EE + e];
    float nrm = dinv[r] * dinv[c];
    atomicAdd(&agg2p[(size_t)r * H2P + j], h2p[(size_t)c * H2P + j] * nrm);
}

__global__ void k_logsoftmax(const float* __restrict__ agg2p, const float* __restrict__ b2,
                             float* __restrict__ out) {
    int i = blockIdx.x * blockDim.x + threadIdx.x;
    if (i >= NN) return;
    const float4* ap = reinterpret_cast<const float4*>(agg2p + (size_t)i * H2P);
    float4 a = ap[0], b = ap[1];
    float v[7] = {a.x, a.y, a.z, a.w, b.x, b.y, b.z};
#pragma unroll
    for (int j = 0; j < 7; ++j) v[j] += b2[j];
    float m = v[0];
#pragma unroll
    for (int j = 1; j < 7; ++j) m = fmaxf(m, v[j]);
    float ssum = 0.f;
#pragma unroll
    for (int j = 0; j < 7; ++j) ssum += expf(v[j] - m);
    float ls = logf(ssum);
#pragma unroll
    for (int j = 0; j < 7; ++j) out[(size_t)i * OUTD + j] = v[j] - m - ls;
}

// ============================ launch ============================

extern "C" void kernel_launch(void* const* d_in, const int* in_sizes, int n_in,
                              void* d_out, int out_size, void* d_ws, size_t ws_size,
                              hipStream_t stream) {
    const float* x  = (const float*)d_in[0];
    const int*   ei = (const int*)d_in[1];     // [2, E] flattened
    const float* W1 = (const float*)d_in[2];
    const float* b1 = (const float*)d_in[3];
    const float* W2 = (const float*)d_in[4];
    const float* b2 = (const float*)d_in[5];
    float* out = (float*)d_out;
    float* ws  = (float*)d_ws;

    float* dinv = ws;                        // N floats
    unsigned short* h1b = (unsigned short*)(ws + NN);   // 16N bf16 = 8N float slots
    float* h2s  = ws + NN + 16 * NN;         // 8N floats (CSR path)

    const size_t need_csr = (size_t)(33 * NN) * 4 + (size_t)(3 * NN + 1 + EE + 64) * 4;
    const bool csr = ws_size >= need_csr;

    if (csr) {
        int* ibase  = (int*)(ws + (size_t)33 * NN);
        int* cnt    = ibase;                 // N
        int* rowptr = ibase + NN;            // N+1
        int* cursor = ibase + 2 * NN + 1;    // N
        int* scol   = ibase + 3 * NN + 1;    // E
        int* bsum   = scol + EE;             // 32
        int* boffs  = bsum + 32;             // 32

        hipLaunchKernelGGL(k_zero_i32, dim3((NN + 255) / 256), dim3(256), 0, stream, cnt, NN);
        hipLaunchKernelGGL(k_count4, dim3((EE / 4 + 255) / 256), dim3(256), 0, stream,
                           ei, cnt);
        hipLaunchKernelGGL(k_scan1, dim3(NB_SCAN), dim3(SCAN_TPB), 0, stream,
                           cnt, rowptr, bsum, dinv);
        hipLaunchKernelGGL(k_scan2, dim3(1), dim3(64), 0, stream, bsum, boffs, rowptr);
        hipLaunchKernelGGL(k_scan3, dim3(NB_SCAN), dim3(SCAN_TPB), 0, stream,
                           boffs, rowptr, cursor);
        hipLaunchKernelGGL(k_place4, dim3((EE / 4 + 255) / 256), dim3(256), 0, stream,
                           ei, cursor, scol);
        hipLaunchKernelGGL(k_gemm1, dim3(NTIL), dim3(256), 0, stream,
                           x, W1, dinv, h1b, (float*)nullptr);
        hipLaunchKernelGGL(k_agg1m, dim3(NN / 4), dim3(256), 0, stream,
                           rowptr, scol, dinv, h1b, b1, W2, h2s);
        hipLaunchKernelGGL(k_agg2, dim3(NN / 4), dim3(256), 0, stream,
                           rowptr, scol, dinv, h2s, b2, out);
    } else {
        // atomic fallback: needs 33N floats + N ints
        float* h1    = ws + NN;              // 16N fp32
        float* agg1  = ws + NN + 16 * NN;    // 16N
        float* h2pf  = h1;                   // 8N over dead h1
        float* agg2p = h1 + 8 * NN;          // 8N
        int* cnt = (int*)agg1;               // dead until after k_dinv_from_cnt
        hipLaunchKernelGGL(k_zero_i32, dim3((NN + 255) / 256), dim3(256), 0, stream, cnt, NN);
        hipLaunchKernelGGL(k_count4, dim3((EE / 4 + 255) / 256), dim3(256), 0, stream,
                           ei, cnt);
        hipLaunchKernelGGL(k_dinv_from_cnt, dim3((NN + 255) / 256), dim3(256), 0, stream,
                           cnt, dinv);
        hipLaunchKernelGGL(k_gemm1, dim3(NTIL), dim3(256), 0, stream,
                           x, W1, (const float*)nullptr, (unsigned short*)nullptr, h1);
        hipLaunchKernelGGL(k_selfloop1, dim3((NN * HID + 255) / 256), dim3(256), 0, stream,
                           h1, dinv, agg1);
        hipLaunchKernelGGL(k_scatter1f, dim3((EE * HID) / 256), dim3(256), 0, stream,
                           ei, dinv, h1, agg1);
        hipLaunchKernelGGL(k_mlp2, dim3((NN + 255) / 256), dim3(256), 0, stream,
                           agg1, b1, W2, dinv, h2pf, agg2p);
        hipLaunchKernelGGL(k_scatter2f, dim3((EE * 8) / 256), dim3(256), 0, stream,
                           ei, dinv, h2pf, agg2p);
        hipLaunchKernelGGL(k_logsoftmax, dim3((NN + 255) / 256), dim3(256), 0, stream,
                           agg2p, b2, out);
    }
}

// Round 8
// 637.592 us; speedup vs baseline: 1.0069x; 1.0069x over previous
//
#include <hip/hip_runtime.h>
#include <hip/hip_bf16.h>

#define NN   100000
#define EE   3200000
#define KDIM 1433
#define HID  16
#define H2P  8
#define OUTD 7

// ---- gemm1 tiling ----
#define KC    128            // elements per chunk
#define RB    64
#define DSTR  67             // dword stride (134 bf16): 67 mod 32 = 3 -> 2-way aliasing = free
#define NCHUNK ((KDIM + KC - 1) / KC)   // 12
#define NTIL  ((NN + RB - 1) / RB)      // 1563 (~= 1536 slots at 6 blocks/CU -> ~single round)

// ---- scan tiling ----
#define SCAN_TPB   1024
#define SCAN_ELEMS 4096
#define NB_SCAN    ((NN + SCAN_ELEMS - 1) / SCAN_ELEMS)   // 25

__device__ inline unsigned short f2bf(float f) {        // fp32 -> bf16 rn
    unsigned u = __float_as_uint(f);
    unsigned r = (u + 0x7FFFu + ((u >> 16) & 1u)) >> 16;
    return (unsigned short)r;
}

// ============================ degree / norm / CSR ============================

__global__ void k_zero_i32(int* __restrict__ p, int n) {
    int i = blockIdx.x * blockDim.x + threadIdx.x;
    if (i < n) p[i] = 0;
}

// 4 edges per thread (EE % 4 == 0)
__global__ void k_count4(const int* __restrict__ ei, int* __restrict__ cnt) {
    int t = blockIdx.x * blockDim.x + threadIdx.x;
    if (t >= EE / 4) return;
    int4 r4 = reinterpret_cast<const int4*>(ei)[t];
    atomicAdd(&cnt[r4.x], 1);
    atomicAdd(&cnt[r4.y], 1);
    atomicAdd(&cnt[r4.z], 1);
    atomicAdd(&cnt[r4.w], 1);
}

__global__ void k_dinv_from_cnt(const int* __restrict__ cnt, float* __restrict__ dinv) {
    int i = blockIdx.x * blockDim.x + threadIdx.x;
    if (i < NN) dinv[i] = rsqrtf((float)cnt[i] + 1.0f);   // +1 self-loop
}

// per-block scan; also emits dinv (fused)
__global__ __launch_bounds__(SCAN_TPB) void k_scan1(const int* __restrict__ cnt,
                                                    int* __restrict__ rowptr,
                                                    int* __restrict__ bsum,
                                                    float* __restrict__ dinv) {
    __shared__ int spart[16];
    const int tid = threadIdx.x;
    const int L = tid & 63;
    const int w = tid >> 6;
    const int i0 = blockIdx.x * SCAN_ELEMS + tid * 4;
    int v0 = (i0 + 0 < NN) ? cnt[i0 + 0] : 0;
    int v1 = (i0 + 1 < NN) ? cnt[i0 + 1] : 0;
    int v2 = (i0 + 2 < NN) ? cnt[i0 + 2] : 0;
    int v3 = (i0 + 3 < NN) ? cnt[i0 + 3] : 0;
    if (i0 + 0 < NN) dinv[i0 + 0] = rsqrtf((float)v0 + 1.0f);
    if (i0 + 1 < NN) dinv[i0 + 1] = rsqrtf((float)v1 + 1.0f);
    if (i0 + 2 < NN) dinv[i0 + 2] = rsqrtf((float)v2 + 1.0f);
    if (i0 + 3 < NN) dinv[i0 + 3] = rsqrtf((float)v3 + 1.0f);
    int local = v0 + v1 + v2 + v3;
    int s = local;
#pragma unroll
    for (int ofs = 1; ofs < 64; ofs <<= 1) {
        int n = __shfl_up(s, ofs, 64);
        if (L >= ofs) s += n;
    }
    if (L == 63) spart[w] = s;
    __syncthreads();
    if (w == 0) {
        int p = (L < 16) ? spart[L] : 0;
#pragma unroll
        for (int ofs = 1; ofs < 16; ofs <<= 1) {
            int n = __shfl_up(p, ofs, 64);
            if (L >= ofs) p += n;
        }
        if (L < 16) spart[L] = p;
    }
    __syncthreads();
    int waveoff = (w > 0) ? spart[w - 1] : 0;
    int excl = waveoff + s - local;                 // block-local exclusive
    if (i0 + 0 < NN) { rowptr[i0 + 0] = excl; excl += v0; }
    if (i0 + 1 < NN) { rowptr[i0 + 1] = excl; excl += v1; }
    if (i0 + 2 < NN) { rowptr[i0 + 2] = excl; excl += v2; }
    if (i0 + 3 < NN) { rowptr[i0 + 3] = excl; excl += v3; }
    if (tid == 0) bsum[blockIdx.x] = spart[15];
}

__global__ void k_scan2(const int* __restrict__ bsum, int* __restrict__ boffs,
                        int* __restrict__ rowptr) {
    int L = threadIdx.x;   // one wave
    int v = (L < NB_SCAN) ? bsum[L] : 0;
    int s = v;
#pragma unroll
    for (int ofs = 1; ofs < 64; ofs <<= 1) {
        int n = __shfl_up(s, ofs, 64);
        if (L >= ofs) s += n;
    }
    if (L < NB_SCAN) boffs[L] = s - v;
    if (L == NB_SCAN - 1) rowptr[NN] = s;          // grand total (=EE)
}

__global__ __launch_bounds__(SCAN_TPB) void k_scan3(const int* __restrict__ boffs,
                                                    int* __restrict__ rowptr,
                                                    int* __restrict__ cursor) {
    const int off = boffs[blockIdx.x];
    const int i0 = blockIdx.x * SCAN_ELEMS + threadIdx.x * 4;
#pragma unroll
    for (int t = 0; t < 4; ++t) {
        int i = i0 + t;
        if (i < NN) {
            int v = rowptr[i] + off;
            rowptr[i] = v;
            cursor[i] = v;
        }
    }
}

// 4 edges per thread
__global__ void k_place4(const int* __restrict__ ei, int* __restrict__ cursor,
                         int* __restrict__ scol) {
    int t = blockIdx.x * blockDim.x + threadIdx.x;
    if (t >= EE / 4) return;
    int4 r4 = reinterpret_cast<const int4*>(ei)[t];
    int4 c4 = reinterpret_cast<const int4*>(ei + EE)[t];
    int p;
    p = atomicAdd(&cursor[r4.x], 1); scol[p] = c4.x;
    p = atomicAdd(&cursor[r4.y], 1); scol[p] = c4.y;
    p = atomicAdd(&cursor[r4.z], 1); scol[p] = c4.z;
    p = atomicAdd(&cursor[r4.w], 1); scol[p] = c4.w;
}

// ============================ layer 1 GEMM ============================

// h1[N][16] = x[N][1433] @ W1[1433][16], 64-row tiles, KC=128 element chunks.
// x staged in LDS as packed bf16 (64 x 67 dwords = 17.2 KB, stride 67 == 3 mod 32
// -> conflict-free) => 6 blocks/CU (launch_bounds 256,6; VGPR cap ~85, no spill):
// 1536 slots vs 1563 tiles => ~single scheduling round (was 1.53 rounds at 34 KB).
// R6-proven pipeline kept: 32-deep load batch, prefetch of chunk c+1 overlaps
// chunk c's FMA phase, 2 barriers per chunk, W1 via wave-uniform s_load.
__global__ __launch_bounds__(256, 6) void k_gemm1(const float* __restrict__ x,
                                                  const float* __restrict__ W1,
                                                  const float* __restrict__ dscale,
                                                  unsigned short* __restrict__ h1b,
                                                  float* __restrict__ h1f) {
    __shared__ __align__(16) unsigned xs2[RB * DSTR];   // 17152 B
    const int tid = threadIdx.x;
    const int wu  = __builtin_amdgcn_readfirstlane(tid >> 6);  // W1 loads -> s_load
    const int L   = tid & 63;
    const int r0  = blockIdx.x * RB;
    const int d     = tid & 63;          // dword column: elements 2d, 2d+1
    const int rbase = tid >> 6;          // 0..3; rows rbase+4m
    const bool fullrows = (r0 + RB) <= NN;

    float ta[16], tb[16];
    float acc[HID];
#pragma unroll
    for (int j = 0; j < HID; ++j) acc[j] = 0.f;

    auto stage = [&](int c) {
        const int c0 = c * KC;
        const int e0 = c0 + 2 * d;
        const float* xp = x + (size_t)(r0 + rbase) * KDIM + e0;
        if (fullrows && (c0 + KC) <= KDIM) {
#pragma unroll
            for (int m = 0; m < 16; ++m) {
                ta[m] = xp[(size_t)(4 * m) * KDIM];
                tb[m] = xp[(size_t)(4 * m) * KDIM + 1];
            }
        } else {
            const bool ok0 = e0 < KDIM, ok1 = (e0 + 1) < KDIM;
#pragma unroll
            for (int m = 0; m < 16; ++m) {
                int gr = r0 + rbase + 4 * m;
                bool g = gr < NN;
                ta[m] = (g && ok0) ? xp[(size_t)(4 * m) * KDIM] : 0.f;
                tb[m] = (g && ok1) ? xp[(size_t)(4 * m) * KDIM + 1] : 0.f;
            }
        }
    };

    stage(0);                            // prologue

    for (int c = 0; c < NCHUNK; ++c) {
        const int c0 = c * KC;
        const int kvalid = (KDIM - c0 < KC) ? (KDIM - c0) : KC;
        __syncthreads();                 // xs2 free (prev compute done)
#pragma unroll
        for (int m = 0; m < 16; ++m) {   // vmcnt drain + cvt happen here
            unsigned pw = (unsigned)f2bf(ta[m]) | ((unsigned)f2bf(tb[m]) << 16);
            xs2[(rbase + 4 * m) * DSTR + d] = pw;
        }
        __syncthreads();

        if (c + 1 < NCHUNK) stage(c + 1);   // prefetch overlaps compute below

        // wave wu covers elements [wu*32, wu*32+32) = dwords [wu*16, wu*16+16)
        int kendw = kvalid - wu * 32;
        kendw = kendw < 0 ? 0 : (kendw > 32 ? 32 : kendw);
        const int ndw = (kendw + 1) >> 1;
        const unsigned* xb = xs2 + L * DSTR + wu * 16;
        const int krow0 = c0 + wu * 32;
#pragma unroll 4
        for (int i = 0; i < ndw; ++i) {
            unsigned dw = xb[i];
            float xlo = __uint_as_float(dw << 16);
            float xhi = __uint_as_float(dw & 0xFFFF0000u);
            int r1 = krow0 + 2 * i + 1;
            r1 = r1 < KDIM ? r1 : (KDIM - 1);       // clamp (xhi==0 there)
            const float* wr0 = W1 + (size_t)(krow0 + 2 * i) * HID;
            const float* wr1 = W1 + (size_t)r1 * HID;
#pragma unroll
            for (int j = 0; j < HID; ++j)
                acc[j] = fmaf(xlo, wr0[j], fmaf(xhi, wr1[j], acc[j]));
        }
    }

    // ---- epilogue: cross-wave k-reduction via LDS (16 KB <= 17.2 KB) ----
    __syncthreads();
    float4* red4 = reinterpret_cast<float4*>(xs2);
    red4[(wu * 64 + L) * 4 + 0] = make_float4(acc[0], acc[1], acc[2], acc[3]);
    red4[(wu * 64 + L) * 4 + 1] = make_float4(acc[4], acc[5], acc[6], acc[7]);
    red4[(wu * 64 + L) * 4 + 2] = make_float4(acc[8], acc[9], acc[10], acc[11]);
    red4[(wu * 64 + L) * 4 + 3] = make_float4(acc[12], acc[13], acc[14], acc[15]);
    __syncthreads();
    int rr = tid >> 2, jj = tid & 3;
    float4 a = red4[(0 * 64 + rr) * 4 + jj];
    float4 b = red4[(1 * 64 + rr) * 4 + jj];
    float4 cf = red4[(2 * 64 + rr) * 4 + jj];
    float4 dd = red4[(3 * 64 + rr) * 4 + jj];
    float4 s = make_float4(a.x + b.x + cf.x + dd.x, a.y + b.y + cf.y + dd.y,
                           a.z + b.z + cf.z + dd.z, a.w + b.w + cf.w + dd.w);
    int gr = r0 + rr;
    if (gr < NN) {
        if (h1b) {
            float sc = dscale[gr];
            unsigned u0 = (unsigned)f2bf(s.x * sc) | ((unsigned)f2bf(s.y * sc) << 16);
            unsigned u1 = (unsigned)f2bf(s.z * sc) | ((unsigned)f2bf(s.w * sc) << 16);
            reinterpret_cast<uint2*>(h1b)[(size_t)gr * 4 + jj] = make_uint2(u0, u1);
        } else {
            reinterpret_cast<float4*>(h1f)[(size_t)gr * 4 + jj] = s;
        }
    }
}

// ============================ fused CSR aggregation + layer-2 matvec ============================

__global__ __launch_bounds__(256) void k_agg1m(const int* __restrict__ rowptr,
                                               const int* __restrict__ scol,
                                               const float* __restrict__ dinv,
                                               const unsigned short* __restrict__ h1b,
                                               const float* __restrict__ b1,
                                               const float* __restrict__ W2,
                                               float* __restrict__ h2s) {
    int row = blockIdx.x * 4 + (threadIdx.x >> 6);
    int L = threadIdx.x & 63;
    int ee = L >> 2;        // 0..15 edge slot
    int q  = L & 3;         // quarter of the 16-feature row
    int s = rowptr[row], eend = rowptr[row + 1];
    float dr = dinv[row];
    const uint2* h1q = reinterpret_cast<const uint2*>(h1b);
    float4 acc = make_float4(0.f, 0.f, 0.f, 0.f);
    for (int k = s + ee; k < eend; k += 16) {
        int c = scol[k];
        uint2 hv = h1q[(size_t)c * 4 + q];
        acc.x += __uint_as_float(hv.x << 16);
        acc.y += __uint_as_float(hv.x & 0xFFFF0000u);
        acc.z += __uint_as_float(hv.y << 16);
        acc.w += __uint_as_float(hv.y & 0xFFFF0000u);
    }
#pragma unroll
    for (int mask = 4; mask <= 32; mask <<= 1) {
        acc.x += __shfl_xor(acc.x, mask, 64);
        acc.y += __shfl_xor(acc.y, mask, 64);
        acc.z += __shfl_xor(acc.z, mask, 64);
        acc.w += __shfl_xor(acc.w, mask, 64);
    }
    uint2 sv = h1q[(size_t)row * 4 + q];          // self term (already *dinv[row])
    acc.x = (acc.x + __uint_as_float(sv.x << 16)) * dr;
    acc.y = (acc.y + __uint_as_float(sv.x & 0xFFFF0000u)) * dr;
    acc.z = (acc.z + __uint_as_float(sv.y << 16)) * dr;
    acc.w = (acc.w + __uint_as_float(sv.y & 0xFFFF0000u)) * dr;
    float v[16];
#pragma unroll
    for (int qq = 0; qq < 4; ++qq) {
        int src = (L & ~3) | qq;
        v[qq * 4 + 0] = __shfl(acc.x, src, 64);
        v[qq * 4 + 1] = __shfl(acc.y, src, 64);
        v[qq * 4 + 2] = __shfl(acc.z, src, 64);
        v[qq * 4 + 3] = __shfl(acc.w, src, 64);
    }
#pragma unroll
    for (int k = 0; k < 16; ++k) v[k] = fmaxf(v[k] + b1[k], 0.f);
    if (L < 8) {
        int j = (L < 7) ? L : 0;
        float o = 0.f;
#pragma unroll
        for (int k = 0; k < 16; ++k) o = fmaf(v[k], W2[k * 7 + j], o);
        h2s[(size_t)row * H2P + L] = (L < 7) ? o * dr : 0.f;
    }
}

__global__ __launch_bounds__(256) void k_agg2(const int* __restrict__ rowptr,
                                              const int* __restrict__ scol,
                                              const float* __restrict__ dinv,
                                              const float* __restrict__ h2s,
                                              const float* __restrict__ b2,
                                              float* __restrict__ out) {
    int row = blockIdx.x * 4 + (threadIdx.x >> 6);
    int L = threadIdx.x & 63;
    int ee = L >> 3, j = L & 7;
    int s = rowptr[row], eend = rowptr[row + 1];
    float dr = dinv[row];
    float acc = 0.f;
    for (int k = s + ee; k < eend; k += 8) {
        int c = scol[k];
        acc += h2s[(size_t)c * H2P + j];
    }
    acc += __shfl_xor(acc, 8, 64);
    acc += __shfl_xor(acc, 16, 64);
    acc += __shfl_xor(acc, 32, 64);
    acc += h2s[(size_t)row * H2P + j];
    float v = acc * dr + ((j < 7) ? b2[j] : 0.f);
    if (j == 7) v = -3.0e38f;
    float m = v;
    m = fmaxf(m, __shfl_xor(m, 1, 64));
    m = fmaxf(m, __shfl_xor(m, 2, 64));
    m = fmaxf(m, __shfl_xor(m, 4, 64));
    float ex = (j < 7) ? expf(v - m) : 0.f;
    float ssum = ex;
    ssum += __shfl_xor(ssum, 1, 64);
    ssum += __shfl_xor(ssum, 2, 64);
    ssum += __shfl_xor(ssum, 4, 64);
    float ls = logf(ssum);
    if (j < 7) out[(size_t)row * OUTD + j] = v - m - ls;
}

// ============================ fallback (small ws): atomic path ============================

__global__ void k_selfloop1(const float* __restrict__ h1, const float* __restrict__ dinv,
                            float* __restrict__ agg1) {
    int t = blockIdx.x * blockDim.x + threadIdx.x;
    if (t >= NN * HID) return;
    int i = t >> 4;
    float di = dinv[i];
    agg1[t] = h1[t] * di * di;
}

__global__ void k_scatter1f(const int* __restrict__ ei, const float* __restrict__ dinv,
                            const float* __restrict__ h1, float* __restrict__ agg1) {
    int t = blockIdx.x * blockDim.x + threadIdx.x;
    int e = t >> 4, j = t & 15;
    if (e >= EE) return;
    int r = ei[e], c = ei[EE + e];
    float nrm = dinv[r] * dinv[c];
    atomicAdd(&agg1[(size_t)r * HID + j], h1[(size_t)c * HID + j] * nrm);
}

__global__ void k_mlp2(const float* __restrict__ agg1, const float* __restrict__ b1,
                       const float* __restrict__ W2, const float* __restrict__ dinv,
                       float* __restrict__ h2p, float* __restrict__ agg2p) {
    int i = blockIdx.x * blockDim.x + threadIdx.x;
    if (i >= NN) return;
    const float4* a4 = reinterpret_cast<const float4*>(agg1 + (size_t)i * HID);
    float4 t0 = a4[0], t1 = a4[1], t2 = a4[2], t3 = a4[3];
    float v[16] = {t0.x, t0.y, t0.z, t0.w, t1.x, t1.y, t1.z, t1.w,
                   t2.x, t2.y, t2.z, t2.w, t3.x, t3.y, t3.z, t3.w};
#pragma unroll
    for (int k = 0; k < 16; ++k) v[k] = fmaxf(v[k] + b1[k], 0.f);
    float o[8] = {0.f, 0.f, 0.f, 0.f, 0.f, 0.f, 0.f, 0.f};
#pragma unroll
    for (int k = 0; k < 16; ++k)
#pragma unroll
        for (int j = 0; j < 7; ++j) o[j] = fmaf(v[k], W2[k * 7 + j], o[j]);
    float4* hp = reinterpret_cast<float4*>(h2p + (size_t)i * H2P);
    hp[0] = make_float4(o[0], o[1], o[2], o[3]);
    hp[1] = make_float4(o[4], o[5], o[6], 0.f);
    if (agg2p) {
        float di = dinv[i];
        float d2 = di * di;
        float4* ap = reinterpret_cast<float4*>(agg2p + (size_t)i * H2P);
        ap[0] = make_float4(o[0] * d2, o[1] * d2, o[2] * d2, o[3] * d2);
        ap[1] = make_float4(o[4] * d2, o[5] * d2, o[6] * d2, 0.f);
    }
}

__global__ void k_scatter2f(const int* __restrict__ ei, const float* __restrict__ dinv,
                            const float* __restrict__ h2p, float* __restrict__ agg2p) {
    int t = blockIdx.x * blockDim.x + threadIdx.x;
    int e = t >> 3, j = t & 7;
    if (e >= EE || j >= OUTD) return;
    int r = ei[e], c = ei[EE + e];
    float nrm = dinv[r] * dinv[c];
    atomicAdd(&agg2p[(size_t)r * H2P + j], h2p[(size_t)c * H2P + j] * nrm);
}

__global__ void k_logsoftmax(const float* __restrict__ agg2p, const float* __restrict__ b2,
                             float* __restrict__ out) {
    int i = blockIdx.x * blockDim.x + threadIdx.x;
    if (i >= NN) return;
    const float4* ap = reinterpret_cast<const float4*>(agg2p + (size_t)i * H2P);
    float4 a = ap[0], b = ap[1];
    float v[7] = {a.x, a.y, a.z, a.w, b.x, b.y, b.z};
#pragma unroll
    for (int j = 0; j < 7; ++j) v[j] += b2[j];
    float m = v[0];
#pragma unroll
    for (int j = 1; j < 7; ++j) m = fmaxf(m, v[j]);
    float ssum = 0.f;
#pragma unroll
    for (int j = 0; j < 7; ++j) ssum += expf(v[j] - m);
    float ls = logf(ssum);
#pragma unroll
    for (int j = 0; j < 7; ++j) out[(size_t)i * OUTD + j] = v[j] - m - ls;
}

// ============================ launch ============================

extern "C" void kernel_launch(void* const* d_in, const int* in_sizes, int n_in,
                              void* d_out, int out_size, void* d_ws, size_t ws_size,
                              hipStream_t stream) {
    const float* x  = (const float*)d_in[0];
    const int*   ei = (const int*)d_in[1];     // [2, E] flattened
    const float* W1 = (const float*)d_in[2];
    const float* b1 = (const float*)d_in[3];
    const float* W2 = (const float*)d_in[4];
    const float* b2 = (const float*)d_in[5];
    float* out = (float*)d_out;
    float* ws  = (float*)d_ws;

    float* dinv = ws;                        // N floats
    unsigned short* h1b = (unsigned short*)(ws + NN);   // 16N bf16 = 8N float slots
    float* h2s  = ws + NN + 16 * NN;         // 8N floats (CSR path)

    const size_t need_csr = (size_t)(33 * NN) * 4 + (size_t)(3 * NN + 1 + EE + 64) * 4;
    const bool csr = ws_size >= need_csr;

    if (csr) {
        int* ibase  = (int*)(ws + (size_t)33 * NN);
        int* cnt    = ibase;                 // N
        int* rowptr = ibase + NN;            // N+1
        int* cursor = ibase + 2 * NN + 1;    // N
        int* scol   = ibase + 3 * NN + 1;    // E
        int* bsum   = scol + EE;             // 32
        int* boffs  = bsum + 32;             // 32

        hipLaunchKernelGGL(k_zero_i32, dim3((NN + 255) / 256), dim3(256), 0, stream, cnt, NN);
        hipLaunchKernelGGL(k_count4, dim3((EE / 4 + 255) / 256), dim3(256), 0, stream,
                           ei, cnt);
        hipLaunchKernelGGL(k_scan1, dim3(NB_SCAN), dim3(SCAN_TPB), 0, stream,
                           cnt, rowptr, bsum, dinv);
        hipLaunchKernelGGL(k_scan2, dim3(1), dim3(64), 0, stream, bsum, boffs, rowptr);
        hipLaunchKernelGGL(k_scan3, dim3(NB_SCAN), dim3(SCAN_TPB), 0, stream,
                           boffs, rowptr, cursor);
        hipLaunchKernelGGL(k_place4, dim3((EE / 4 + 255) / 256), dim3(256), 0, stream,
                           ei, cursor, scol);
        hipLaunchKernelGGL(k_gemm1, dim3(NTIL), dim3(256), 0, stream,
                           x, W1, dinv, h1b, (float*)nullptr);
        hipLaunchKernelGGL(k_agg1m, dim3(NN / 4), dim3(256), 0, stream,
                           rowptr, scol, dinv, h1b, b1, W2, h2s);
        hipLaunchKernelGGL(k_agg2, dim3(NN / 4), dim3(256), 0, stream,
                           rowptr, scol, dinv, h2s, b2, out);
    } else {
        // atomic fallback: needs 33N floats + N ints
        float* h1    = ws + NN;              // 16N fp32
        float* agg1  = ws + NN + 16 * NN;    // 16N
        float* h2pf  = h1;                   // 8N over dead h1
        float* agg2p = h1 + 8 * NN;          // 8N
        int* cnt = (int*)agg1;               // dead until after k_dinv_from_cnt
        hipLaunchKernelGGL(k_zero_i32, dim3((NN + 255) / 256), dim3(256), 0, stream, cnt, NN);
        hipLaunchKernelGGL(k_count4, dim3((EE / 4 + 255) / 256), dim3(256), 0, stream,
                           ei, cnt);
        hipLaunchKernelGGL(k_dinv_from_cnt, dim3((NN + 255) / 256), dim3(256), 0, stream,
                           cnt, dinv);
        hipLaunchKernelGGL(k_gemm1, dim3(NTIL), dim3(256), 0, stream,
                           x, W1, (const float*)nullptr, (unsigned short*)nullptr, h1);
        hipLaunchKernelGGL(k_selfloop1, dim3((NN * HID + 255) / 256), dim3(256), 0, stream,
                           h1, dinv, agg1);
        hipLaunchKernelGGL(k_scatter1f, dim3((EE * HID) / 256), dim3(256), 0, stream,
                           ei, dinv, h1, agg1);
        hipLaunchKernelGGL(k_mlp2, dim3((NN + 255) / 256), dim3(256), 0, stream,
                           agg1, b1, W2, dinv, h2pf, agg2p);
        hipLaunchKernelGGL(k_scatter2f, dim3((EE * 8) / 256), dim3(256), 0, stream,
                           ei, dinv, h2pf, agg2p);
        hipLaunchKernelGGL(k_logsoftmax, dim3((NN + 255) / 256), dim3(256), 0, stream,
                           agg2p, b2, out);
    }
}